// Round 4
// baseline (145.357 us; speedup 1.0000x reference)
//
#include <hip/hip_runtime.h>

typedef unsigned short ushort_t;
typedef unsigned int uint_t;

typedef __bf16 bf16x8 __attribute__((ext_vector_type(8)));
typedef float f32x4 __attribute__((ext_vector_type(4)));

#define KK 588       // true K
#define KP 608       // padded K (19 * 32)
#define NN 1152      // N (output cols)
#define MM 32768     // M (output rows)
#define POSROWS 4096 // h*w per image
#define NSTEP 19     // KP/32
#define BM 256
#define BN 128
#define GRID 1152    // (MM/256) * (NN/128) = 128 * 9, divisible by 8
#define CHUNKS_PER_ROW 76 // KP/8

// ---------------- helpers ----------------

__device__ __forceinline__ void cubic_taps(int dst, float* w, int* idx) {
    const float A = -0.75f;
    float src = (float)dst * 0.25f - 0.25f;   // (dst+0.5)*16/64 - 0.5
    int x0 = (int)floorf(src);
    #pragma unroll
    for (int k = -1; k <= 2; ++k) {
        int i = x0 + k;
        int ic = i < 0 ? 0 : (i > 15 ? 15 : i);
        float d = fabsf(src - (float)i);
        float wt;
        if (d <= 1.0f)      wt = ((A + 2.0f) * d - (A + 3.0f)) * d * d + 1.0f;
        else if (d < 2.0f)  wt = ((A * d - 5.0f * A) * d + 8.0f * A) * d - 4.0f * A;
        else                wt = 0.0f;
        w[k + 1] = wt;
        idx[k + 1] = ic;
    }
}

// ---------------- pos embedding: (4096, 1152) fp32 into ws ----------------

__global__ void pos_kernel(const float* __restrict__ pt, float* __restrict__ pos) {
    int n = blockIdx.x; // 0..4095 (rearranged row)
    int h = ((n >> 7) << 1) | ((n >> 1) & 1);
    int w = (((n >> 2) & 31) << 1) | (n & 1);
    float wh[4], ww[4];
    int ih[4], iw[4];
    cubic_taps(h, wh, ih);
    cubic_taps(w, ww, iw);
    int tid = threadIdx.x;
    if (tid >= NN / 4) return;
    const f32x4* pt4 = (const f32x4*)pt;
    f32x4 s = {0.f, 0.f, 0.f, 0.f};
    #pragma unroll
    for (int a = 0; a < 4; ++a) {
        #pragma unroll
        for (int b = 0; b < 4; ++b) {
            float wt = wh[a] * ww[b];
            f32x4 v = pt4[(ih[a] * 16 + iw[b]) * (NN / 4) + tid];
            s.x += wt * v.x; s.y += wt * v.y; s.z += wt * v.z; s.w += wt * v.w;
        }
    }
    ((f32x4*)pos)[(size_t)n * (NN / 4) + tid] = s;
}

// ---------------- f32 -> bf16 (A and B in one launch), K 588 -> 608 ----------------

__global__ void cvt_pad_kernel(const float* __restrict__ srcA, ushort_t* __restrict__ dstA,
                               const float* __restrict__ srcB, ushort_t* __restrict__ dstB) {
    int c = blockIdx.x * 256 + threadIdx.x; // chunk id, 8 elems each
    const int ca = MM * CHUNKS_PER_ROW;
    const float* src;
    ushort_t* dst;
    if (c < ca) { src = srcA; dst = dstA; }
    else {
        c -= ca;
        if (c >= NN * CHUNKS_PER_ROW) return;
        src = srcB; dst = dstB;
    }
    int row = c / CHUNKS_PER_ROW;
    int k0 = (c - row * CHUNKS_PER_ROW) * 8;
    const float* g = src + (size_t)row * KK + k0;
    bf16x8 v;
    if (k0 + 8 <= KK) {
        f32x4 a = *(const f32x4*)g;
        f32x4 b = *(const f32x4*)(g + 4);
        #pragma unroll
        for (int e = 0; e < 4; ++e) { v[e] = (__bf16)a[e]; v[e + 4] = (__bf16)b[e]; }
    } else {
        #pragma unroll
        for (int e = 0; e < 8; ++e)
            v[e] = (k0 + e < KK) ? (__bf16)g[e] : (__bf16)0.f;
    }
    *(bf16x8*)(dst + (size_t)row * KP + k0) = v;
}

// ---------------- bf16 MFMA GEMM + bias + pos epilogue ----------------
// Tile 256x128, 4 waves (2m x 2n), wave = 128x64 (m_rep=8, n_rep=4).
// Operands SWAPPED in mfma (bfr, af) so the C-fragment quad spans 4 consecutive
// output COLUMNS -> float4 epilogue. 3-deep global_load_lds pipeline (counted
// vmcnt) + counted-lgkm MFMA/ds_read interleave + setprio.

__global__ __launch_bounds__(256, 2)
void gemm_kernel(const ushort_t* __restrict__ Abf,
                 const ushort_t* __restrict__ Bbf,
                 const float* __restrict__ bias,
                 const float* __restrict__ pos,
                 float* __restrict__ out) {
    __shared__ __align__(16) ushort_t lA[3][BM * 32]; // 16KB per buf, 16B slots swizzled
    __shared__ __align__(16) ushort_t lB[3][BN * 32]; // 8KB per buf

    const int t = threadIdx.x;
    const int lane = t & 63;
    const int lm = lane & 15;
    const int lq = (lane >> 4);
    const int wid = t >> 6;
    const int wm = wid >> 1, wn = wid & 1;

    // bijective XCD-chunked swizzle: 1152 = 8 XCDs x 144
    int linear = (int)blockIdx.x;
    int xcd = linear & 7;
    int local = linear >> 3;
    int wg = xcd * (GRID / 8) + local;
    int mt = wg / 9;
    int nt = wg - mt * 9;
    const int bm = mt * BM;
    const int bn = nt * BN;

    f32x4 acc[8][4] = {};

    auto stage = [&](int ks, int buf) {
        const int k0 = ks * 32;
        #pragma unroll
        for (int j = 0; j < 4; ++j) { // A: 256 rows x 32k = 16KB -> 4 loads/thread
            int idx = j * 256 + t;
            int row = idx >> 2;
            int slot = idx & 3;
            int khi = slot ^ ((row >> 1) & 3); // inverse swizzle on SOURCE (lds dest linear)
            const ushort_t* gA = Abf + (size_t)(bm + row) * KP + k0 + khi * 8;
            ushort_t* lAp = &lA[buf][(size_t)(idx & ~63) * 8];
            __builtin_amdgcn_global_load_lds(
                (const __attribute__((address_space(1))) void*)gA,
                (__attribute__((address_space(3))) void*)lAp, 16, 0, 0);
        }
        #pragma unroll
        for (int j = 0; j < 2; ++j) { // B: 128 rows x 32k = 8KB -> 2 loads/thread
            int idx = j * 256 + t;
            int row = idx >> 2;
            int slot = idx & 3;
            int khi = slot ^ ((row >> 1) & 3);
            const ushort_t* gB = Bbf + (size_t)(bn + row) * KP + k0 + khi * 8;
            ushort_t* lBp = &lB[buf][(size_t)(idx & ~63) * 8];
            __builtin_amdgcn_global_load_lds(
                (const __attribute__((address_space(1))) void*)gB,
                (__attribute__((address_space(3))) void*)lBp, 16, 0, 0);
        }
    };

    // prologue: 2 tiles in flight (6 loads each)
    stage(0, 0);
    stage(1, 1);

    for (int ks = 0; ks < NSTEP; ++ks) {
        const int cur = ks % 3;

        if (ks + 2 < NSTEP) {
            stage(ks + 2, (ks + 2) % 3);
            asm volatile("s_waitcnt vmcnt(12)" ::: "memory"); // tile ks landed
        } else if (ks + 1 < NSTEP) {
            asm volatile("s_waitcnt vmcnt(6)" ::: "memory");
        } else {
            asm volatile("s_waitcnt vmcnt(0)" ::: "memory");
        }
        __builtin_amdgcn_s_barrier();
        __builtin_amdgcn_sched_barrier(0);

        bf16x8 af[8], bfr[4];
        // G0: all 4 B-frags + A0,A1 (6 reads) -- cluster 0's operands
        #pragma unroll
        for (int ni = 0; ni < 4; ++ni) {
            int row = wn * 64 + ni * 16 + lm;
            int slot = lq ^ ((row >> 1) & 3);
            bfr[ni] = *(const bf16x8*)(&lB[cur][row * 32 + slot * 8]);
        }
        #pragma unroll
        for (int mi = 0; mi < 2; ++mi) {
            int row = wm * 128 + mi * 16 + lm;
            int slot = lq ^ ((row >> 1) & 3);
            af[mi] = *(const bf16x8*)(&lA[cur][row * 32 + slot * 8]);
        }
        __builtin_amdgcn_sched_barrier(0);
        // G1..G3: A2..A7 in pairs, order pinned for counted lgkm waits
        #pragma unroll
        for (int g = 1; g < 4; ++g) {
            #pragma unroll
            for (int mi = 2 * g; mi < 2 * g + 2; ++mi) {
                int row = wm * 128 + mi * 16 + lm;
                int slot = lq ^ ((row >> 1) & 3);
                af[mi] = *(const bf16x8*)(&lA[cur][row * 32 + slot * 8]);
            }
            __builtin_amdgcn_sched_barrier(0);
        }

        // 4 MFMA clusters of 8, gated by counted lgkmcnt (DS returns in order)
        #pragma unroll
        for (int c = 0; c < 4; ++c) {
            if (c == 0)      asm volatile("s_waitcnt lgkmcnt(6)" ::: "memory");
            else if (c == 1) asm volatile("s_waitcnt lgkmcnt(4)" ::: "memory");
            else if (c == 2) asm volatile("s_waitcnt lgkmcnt(2)" ::: "memory");
            else             asm volatile("s_waitcnt lgkmcnt(0)" ::: "memory");
            __builtin_amdgcn_sched_barrier(0);
            __builtin_amdgcn_s_setprio(1);
            #pragma unroll
            for (int mi = 2 * c; mi < 2 * c + 2; ++mi)
                #pragma unroll
                for (int ni = 0; ni < 4; ++ni)
                    acc[mi][ni] = __builtin_amdgcn_mfma_f32_16x16x32_bf16(
                        bfr[ni], af[mi], acc[mi][ni], 0, 0, 0); // SWAPPED operands
            __builtin_amdgcn_s_setprio(0);
        }
        __builtin_amdgcn_sched_barrier(0);
        __builtin_amdgcn_s_barrier(); // lgkmcnt(0) above already drained our ds_reads
    }

    // epilogue: swapped C-layout => lane holds out[m][nb..nb+3] per frag
    // m = bm + wm*128 + mi*16 + lm ; nb = bn + wn*64 + ni*16 + lq*4
    const int N0 = bn + wn * 64;
    const int M0 = bm + wm * 128;
    f32x4 bias4[4];
    #pragma unroll
    for (int ni = 0; ni < 4; ++ni)
        bias4[ni] = *(const f32x4*)(bias + N0 + ni * 16 + lq * 4);
    #pragma unroll
    for (int mi = 0; mi < 8; ++mi) {
        int m = M0 + mi * 16 + lm;
        const float* posrow = pos + (size_t)(m & (POSROWS - 1)) * NN;
        float* outrow = out + (size_t)m * NN;
        #pragma unroll
        for (int ni = 0; ni < 4; ++ni) {
            int nb = N0 + ni * 16 + lq * 4;
            f32x4 p = *(const f32x4*)(posrow + nb);
            f32x4 v = acc[mi][ni];
            v.x += bias4[ni].x + p.x;
            v.y += bias4[ni].y + p.y;
            v.z += bias4[ni].z + p.z;
            v.w += bias4[ni].w + p.w;
            *(f32x4*)(outrow + nb) = v;
        }
    }
}

// ---------------- fallback (ws too small): naive fp32 ----------------

__global__ void fb_kernel(const float* __restrict__ A, const float* __restrict__ W,
                          const float* __restrict__ bias, const float* __restrict__ pt,
                          float* __restrict__ out) {
    __shared__ float sA[16][17], sB[16][17];
    int ty = threadIdx.y, tx = threadIdx.x;
    int row = blockIdx.y * 16 + ty; // M
    int col = blockIdx.x * 16 + tx; // N
    float acc = 0.f;
    for (int k0 = 0; k0 < KK; k0 += 16) {
        int ka = k0 + tx;
        sA[ty][tx] = (ka < KK) ? A[(size_t)row * KK + ka] : 0.f;
        sB[ty][tx] = (ka < KK) ? W[(size_t)(blockIdx.x * 16 + ty) * KK + ka] : 0.f;
        __syncthreads();
        #pragma unroll
        for (int kk = 0; kk < 16; ++kk)
            acc += sA[ty][kk] * sB[tx][kk];
        __syncthreads();
    }
    int n = row & (POSROWS - 1);
    int h = ((n >> 7) << 1) | ((n >> 1) & 1);
    int w = (((n >> 2) & 31) << 1) | (n & 1);
    float wh[4], ww[4]; int ih[4], iw[4];
    cubic_taps(h, wh, ih);
    cubic_taps(w, ww, iw);
    float p = 0.f;
    #pragma unroll
    for (int a = 0; a < 4; ++a) {
        float rs = 0.f;
        #pragma unroll
        for (int b = 0; b < 4; ++b)
            rs += ww[b] * pt[(ih[a] * 16 + iw[b]) * NN + col];
        p += wh[a] * rs;
    }
    out[(size_t)row * NN + col] = acc + bias[col] + p;
}

// ---------------- launch ----------------

extern "C" void kernel_launch(void* const* d_in, const int* in_sizes, int n_in,
                              void* d_out, int out_size, void* d_ws, size_t ws_size,
                              hipStream_t stream) {
    const float* pv   = (const float*)d_in[0]; // (32768, 588)
    const float* wp   = (const float*)d_in[1]; // (1152, 588)
    const float* bias = (const float*)d_in[2]; // (1152,)
    const float* pt   = (const float*)d_in[3]; // (256, 1152)
    float* out = (float*)d_out;

    const size_t pos_bytes = (size_t)POSROWS * NN * 4;   // 18,874,368
    const size_t pvb_bytes = (size_t)MM * KP * 2;        // 39,845,888
    const size_t wb_bytes  = (size_t)NN * KP * 2;        //  1,400,832
    const size_t need = pos_bytes + pvb_bytes + wb_bytes;

    if (ws_size >= need) {
        float* pos = (float*)d_ws;
        ushort_t* pvb = (ushort_t*)((char*)d_ws + pos_bytes);
        ushort_t* wb  = (ushort_t*)((char*)d_ws + pos_bytes + pvb_bytes);

        pos_kernel<<<POSROWS, 320, 0, stream>>>(pt, pos);

        int chunks = (MM + NN) * CHUNKS_PER_ROW;
        cvt_pad_kernel<<<(chunks + 255) / 256, 256, 0, stream>>>(pv, pvb, wp, wb);

        gemm_kernel<<<GRID, 256, 0, stream>>>(pvb, wb, bias, pos, out);
    } else {
        fb_kernel<<<dim3(NN / 16, MM / 16), dim3(16, 16), 0, stream>>>(pv, wp, bias, pt, out);
    }
}

// Round 5
// 140.217 us; speedup vs baseline: 1.0367x; 1.0367x over previous
//
#include <hip/hip_runtime.h>

typedef unsigned short ushort_t;
typedef unsigned int uint_t;

typedef __bf16 bf16x8 __attribute__((ext_vector_type(8)));
typedef float f32x4 __attribute__((ext_vector_type(4)));

#define KK 588       // true K
#define KP 608       // padded K (19 * 32) -- B only
#define NN 1152      // N (output cols)
#define MM 32768     // M (output rows)
#define POSROWS 4096 // h*w per image
#define NSTEP 19     // KP/32
#define GRID 2304    // (MM/128) * (NN/128) = 256 * 9
#define CHUNKS_PER_ROW 76          // KP/8
#define BCHUNKS (NN * CHUNKS_PER_ROW)   // 87552
#define BBLOCKS ((BCHUNKS + 255) / 256) // 342

// ---------------- helpers ----------------

__device__ __forceinline__ void cubic_taps(int dst, float* w, int* idx) {
    const float A = -0.75f;
    float src = (float)dst * 0.25f - 0.25f;   // (dst+0.5)*16/64 - 0.5
    int x0 = (int)floorf(src);
    #pragma unroll
    for (int k = -1; k <= 2; ++k) {
        int i = x0 + k;
        int ic = i < 0 ? 0 : (i > 15 ? 15 : i);
        float d = fabsf(src - (float)i);
        float wt;
        if (d <= 1.0f)      wt = ((A + 2.0f) * d - (A + 3.0f)) * d * d + 1.0f;
        else if (d < 2.0f)  wt = ((A * d - 5.0f * A) * d + 8.0f * A) * d - 4.0f * A;
        else                wt = 0.0f;
        w[k + 1] = wt;
        idx[k + 1] = ic;
    }
}

// ---------------- prep: cvt B (fp32->bf16, pad to KP) + pos table (+bias) ----------------

__global__ void prep_kernel(const float* __restrict__ wp, ushort_t* __restrict__ wb,
                            const float* __restrict__ pt, const float* __restrict__ bias,
                            float* __restrict__ pos) {
    int b = blockIdx.x;
    if (b < BBLOCKS) {
        // B conversion: (1152, 588) fp32 -> (1152, 608) bf16
        int c = b * 256 + threadIdx.x;
        if (c >= BCHUNKS) return;
        int row = c / CHUNKS_PER_ROW;
        int k0 = (c - row * CHUNKS_PER_ROW) * 8;
        const float* g = wp + (size_t)row * KK + k0;
        bf16x8 v;
        if (k0 + 8 <= KK) {
            f32x4 a = *(const f32x4*)g;
            f32x4 bb = *(const f32x4*)(g + 4);
            #pragma unroll
            for (int e = 0; e < 4; ++e) { v[e] = (__bf16)a[e]; v[e + 4] = (__bf16)bb[e]; }
        } else {
            #pragma unroll
            for (int e = 0; e < 8; ++e)
                v[e] = (k0 + e < KK) ? (__bf16)g[e] : (__bf16)0.f;
        }
        *(bf16x8*)(wb + (size_t)row * KP + k0) = v;
    } else {
        // pos row (rearranged) with bias folded in
        int n = b - BBLOCKS; // 0..4095
        int h = ((n >> 7) << 1) | ((n >> 1) & 1);
        int w = (((n >> 2) & 31) << 1) | (n & 1);
        float wh[4], ww[4];
        int ih[4], iw[4];
        cubic_taps(h, wh, ih);
        cubic_taps(w, ww, iw);
        const f32x4* pt4 = (const f32x4*)pt;
        const f32x4* bias4 = (const f32x4*)bias;
        for (int j = threadIdx.x; j < NN / 4; j += blockDim.x) {
            f32x4 s = bias4[j];
            #pragma unroll
            for (int a = 0; a < 4; ++a) {
                #pragma unroll
                for (int bq = 0; bq < 4; ++bq) {
                    float wt = wh[a] * ww[bq];
                    f32x4 vv = pt4[(ih[a] * 16 + iw[bq]) * (NN / 4) + j];
                    s.x += wt * vv.x; s.y += wt * vv.y; s.z += wt * vv.z; s.w += wt * vv.w;
                }
            }
            ((f32x4*)pos)[(size_t)n * (NN / 4) + j] = s;
        }
    }
}

// ---------------- fused GEMM: A fp32 read + in-kernel cvt, bf16 MFMA ----------------
// A: [MM][KK] fp32, B: [NN][KP] bf16. out[m][n] = sum_k A[m][k]*B[n][k] + pos[m&4095][n]
// Depth-2 A register pipeline: load(ks+2) -> cvt+ds_write(ks+1) -> consume(ks).
// B: 3-buf global_load_lds staged 2 ahead. One barrier per K-step, counted vmcnt.

__global__ __launch_bounds__(256, 3)
void gemm_kernel(const float* __restrict__ A,
                 const ushort_t* __restrict__ Bbf,
                 const float* __restrict__ pos,
                 float* __restrict__ out) {
    __shared__ __align__(16) ushort_t lA[2][128 * 32]; // 8KB/buf, 16B slots swizzled
    __shared__ __align__(16) ushort_t lB[3][128 * 32];

    const int t = threadIdx.x;
    const int lane = t & 63;
    const int lm = lane & 15;
    const int lq = lane >> 4;
    const int wid = t >> 6;
    const int wm = wid >> 1, wn = wid & 1;

    // A staging geometry: 2 threads/row, 16 floats each
    const int arow = t >> 1;
    const int akh = (t & 1) * 16;      // k offset in floats
    const int asw = (arow >> 1) & 3;   // row swizzle
    const int aq0 = (t & 1) * 2;       // first 8-elem slot

    // bijective XCD-chunked swizzle: 2304 = 8 XCDs x 288
    int linear = (int)blockIdx.x;
    int xcd = linear & 7;
    int local = linear >> 3;
    int wg = xcd * (GRID / 8) + local;
    int mt = wg / 9;
    int nt = wg - mt * 9;
    const int bm = mt * 128;
    const int bn = nt * 128;

    f32x4 acc[4][4] = {};
    f32x4 rA0[4], rA1[4];

    auto loadA_fast = [&](int ks, f32x4* r) {
        const float* g = A + (size_t)(bm + arow) * KK + ks * 32 + akh;
        r[0] = *(const f32x4*)g;
        r[1] = *(const f32x4*)(g + 4);
        r[2] = *(const f32x4*)(g + 8);
        r[3] = *(const f32x4*)(g + 12);
    };
    auto loadA_guard = [&](int ks, f32x4* r) { // tile 18: k 576..607, valid < 588
        const float* gr = A + (size_t)(bm + arow) * KK;
        int kb = ks * 32 + akh;
        #pragma unroll
        for (int e = 0; e < 16; ++e) {
            int k = kb + e;
            r[e >> 2][e & 3] = (k < KK) ? gr[k] : 0.f;
        }
    };
    auto cvtwrA = [&](int tile, const f32x4* r) {
        bf16x8 v0, v1;
        #pragma unroll
        for (int e = 0; e < 4; ++e) { v0[e] = (__bf16)r[0][e]; v0[e + 4] = (__bf16)r[1][e]; }
        #pragma unroll
        for (int e = 0; e < 4; ++e) { v1[e] = (__bf16)r[2][e]; v1[e + 4] = (__bf16)r[3][e]; }
        ushort_t* base = &lA[tile & 1][arow * 32];
        *(bf16x8*)(base + (aq0 ^ asw) * 8) = v0;
        *(bf16x8*)(base + ((aq0 + 1) ^ asw) * 8) = v1;
    };
    auto stageB = [&](int ks, int buf) {
        const int k0 = ks * 32;
        #pragma unroll
        for (int j = 0; j < 2; ++j) {
            int idx = j * 256 + t;
            int row = idx >> 2;
            int slot = idx & 3;
            int khi = slot ^ ((row >> 1) & 3); // inverse swizzle on SOURCE (lds dest linear)
            const ushort_t* gB = Bbf + (size_t)(bn + row) * KP + k0 + khi * 8;
            ushort_t* lBp = &lB[buf][(size_t)(idx & ~63) * 8]; // wave-uniform base
            __builtin_amdgcn_global_load_lds(
                (const __attribute__((address_space(1))) void*)gB,
                (__attribute__((address_space(3))) void*)lBp, 16, 0, 0);
        }
    };

    auto step = [&](int ks, f32x4* rload, f32x4* rcvt) {
        const bool issue = (ks + 2 < NSTEP);
        if (issue) {
            if (ks + 2 == NSTEP - 1) loadA_guard(ks + 2, rload);
            else                     loadA_fast(ks + 2, rload);
            stageB(ks + 2, (ks + 2) % 3);
        }
        __builtin_amdgcn_sched_barrier(0); // loads issued before compute

        bf16x8 af[4], bfr[4];
        const ushort_t* bufA = lA[ks & 1];
        const ushort_t* bufB = lB[ks % 3];
        #pragma unroll
        for (int mi = 0; mi < 4; ++mi) {
            int row = wm * 64 + mi * 16 + lm;
            int slot = lq ^ ((row >> 1) & 3);
            af[mi] = *(const bf16x8*)(bufA + row * 32 + slot * 8);
        }
        #pragma unroll
        for (int ni = 0; ni < 4; ++ni) {
            int row = wn * 64 + ni * 16 + lm;
            int slot = lq ^ ((row >> 1) & 3);
            bfr[ni] = *(const bf16x8*)(bufB + row * 32 + slot * 8);
        }
        #pragma unroll
        for (int mi = 0; mi < 4; ++mi)
            #pragma unroll
            for (int ni = 0; ni < 4; ++ni)
                acc[mi][ni] = __builtin_amdgcn_mfma_f32_16x16x32_bf16(
                    bfr[ni], af[mi], acc[mi][ni], 0, 0, 0); // swapped -> col-quad C layout

        if (issue) asm volatile("s_waitcnt vmcnt(6)" ::: "memory"); // prev-step loads done
        else       asm volatile("s_waitcnt vmcnt(0)" ::: "memory");
        if (ks + 1 < NSTEP) cvtwrA(ks + 1, rcvt);
        asm volatile("s_waitcnt lgkmcnt(0)" ::: "memory");
        __builtin_amdgcn_s_barrier();
    };

    // prologue: tile0 -> regs -> LDS; tile1 -> regs; B0,B1 staged
    loadA_fast(0, rA0); stageB(0, 0);
    loadA_fast(1, rA1); stageB(1, 1);
    asm volatile("s_waitcnt vmcnt(6)" ::: "memory"); // tile0 A + B0 landed
    cvtwrA(0, rA0);
    asm volatile("s_waitcnt lgkmcnt(0)" ::: "memory");
    __builtin_amdgcn_s_barrier();

    for (int ks = 0; ks < NSTEP - 2; ks += 2) { // ks = 0,2,...,16 -> steps 0..17
        step(ks, rA0, rA1);      // load tile ks+2 -> rA0, cvt tile ks+1 from rA1
        step(ks + 1, rA1, rA0);  // load tile ks+3 -> rA1, cvt tile ks+2 from rA0
    }

    { // peeled step 18: everything resident (lA[0], lB[0]); no staging
        bf16x8 af[4], bfr[4];
        const ushort_t* bufA = lA[0];
        const ushort_t* bufB = lB[0];
        #pragma unroll
        for (int mi = 0; mi < 4; ++mi) {
            int row = wm * 64 + mi * 16 + lm;
            int slot = lq ^ ((row >> 1) & 3);
            af[mi] = *(const bf16x8*)(bufA + row * 32 + slot * 8);
        }
        #pragma unroll
        for (int ni = 0; ni < 4; ++ni) {
            int row = wn * 64 + ni * 16 + lm;
            int slot = lq ^ ((row >> 1) & 3);
            bfr[ni] = *(const bf16x8*)(bufB + row * 32 + slot * 8);
        }
        #pragma unroll
        for (int mi = 0; mi < 4; ++mi)
            #pragma unroll
            for (int ni = 0; ni < 4; ++ni)
                acc[mi][ni] = __builtin_amdgcn_mfma_f32_16x16x32_bf16(
                    bfr[ni], af[mi], acc[mi][ni], 0, 0, 0);
    }

    // epilogue: swapped C-layout -> lane holds out[m][nb..nb+3]; bias folded in pos
    const int M0 = bm + wm * 64;
    const int N0 = bn + wn * 64;
    #pragma unroll
    for (int mi = 0; mi < 4; ++mi) {
        int m = M0 + mi * 16 + lm;
        const float* posrow = pos + (size_t)(m & (POSROWS - 1)) * NN;
        float* outrow = out + (size_t)m * NN;
        #pragma unroll
        for (int ni = 0; ni < 4; ++ni) {
            int nb = N0 + ni * 16 + lq * 4;
            f32x4 p = *(const f32x4*)(posrow + nb);
            f32x4 v = acc[mi][ni];
            v.x += p.x; v.y += p.y; v.z += p.z; v.w += p.w;
            *(f32x4*)(outrow + nb) = v;
        }
    }
}

// ---------------- fallback (ws too small): naive fp32 ----------------

__global__ void fb_kernel(const float* __restrict__ A, const float* __restrict__ W,
                          const float* __restrict__ bias, const float* __restrict__ pt,
                          float* __restrict__ out) {
    __shared__ float sA[16][17], sB[16][17];
    int ty = threadIdx.y, tx = threadIdx.x;
    int row = blockIdx.y * 16 + ty; // M
    int col = blockIdx.x * 16 + tx; // N
    float acc = 0.f;
    for (int k0 = 0; k0 < KK; k0 += 16) {
        int ka = k0 + tx;
        sA[ty][tx] = (ka < KK) ? A[(size_t)row * KK + ka] : 0.f;
        sB[ty][tx] = (ka < KK) ? W[(size_t)(blockIdx.x * 16 + ty) * KK + ka] : 0.f;
        __syncthreads();
        #pragma unroll
        for (int kk = 0; kk < 16; ++kk)
            acc += sA[ty][kk] * sB[tx][kk];
        __syncthreads();
    }
    int n = row & (POSROWS - 1);
    int h = ((n >> 7) << 1) | ((n >> 1) & 1);
    int w = (((n >> 2) & 31) << 1) | (n & 1);
    float wh[4], ww[4]; int ih[4], iw[4];
    cubic_taps(h, wh, ih);
    cubic_taps(w, ww, iw);
    float p = 0.f;
    #pragma unroll
    for (int a = 0; a < 4; ++a) {
        float rs = 0.f;
        #pragma unroll
        for (int b = 0; b < 4; ++b)
            rs += ww[b] * pt[(ih[a] * 16 + iw[b]) * NN + col];
        p += wh[a] * rs;
    }
    out[(size_t)row * NN + col] = acc + bias[col] + p;
}

// ---------------- launch ----------------

extern "C" void kernel_launch(void* const* d_in, const int* in_sizes, int n_in,
                              void* d_out, int out_size, void* d_ws, size_t ws_size,
                              hipStream_t stream) {
    const float* pv   = (const float*)d_in[0]; // (32768, 588)
    const float* wp   = (const float*)d_in[1]; // (1152, 588)
    const float* bias = (const float*)d_in[2]; // (1152,)
    const float* pt   = (const float*)d_in[3]; // (256, 1152)
    float* out = (float*)d_out;

    const size_t pos_bytes = (size_t)POSROWS * NN * 4;   // 18,874,368
    const size_t wb_bytes  = (size_t)NN * KP * 2;        //  1,400,832
    const size_t need = pos_bytes + wb_bytes;

    if (ws_size >= need) {
        float* pos = (float*)d_ws;
        ushort_t* wb = (ushort_t*)((char*)d_ws + pos_bytes);

        prep_kernel<<<BBLOCKS + POSROWS, 256, 0, stream>>>(wp, wb, pt, bias, pos);
        gemm_kernel<<<GRID, 256, 0, stream>>>(pv, wb, pos, out);
    } else {
        fb_kernel<<<dim3(NN / 16, MM / 16), dim3(16, 16), 0, stream>>>(pv, wp, bias, pt, out);
    }
}